// Round 4
// baseline (137.753 us; speedup 1.0000x reference)
//
#include <hip/hip_runtime.h>
#include <hip/hip_bf16.h>

// B=16, T=32, N=8192. pred/cenp: [B,T,N,3] f32; dofs: [B,T,4] f32; ptrans: [B,T,3] f32.
// out: [B,T,N,3] f32.  out = (pred - cenp) @ R(q) + ptrans + cenp   (row-vector convention)

#define N_PTS 8192  // points per (b,t)

__global__ __launch_bounds__(256) void tooth_assembler_kernel(
    const float* __restrict__ pred,
    const float* __restrict__ cenp,
    const float* __restrict__ dofs,
    const float* __restrict__ ptrans,
    float* __restrict__ out,
    int total_groups)  // total points / 4
{
    int g = blockIdx.x * blockDim.x + threadIdx.x;
    if (g >= total_groups) return;

    int pt0 = g * 4;             // first point handled by this thread
    int bt  = pt0 >> 13;         // / N_PTS (8192) — uniform across the 4 points

    // Quaternion -> rotation matrix (real-part-first: r,i,j,k)
    const float4 q = *reinterpret_cast<const float4*>(dofs + bt * 4);
    float r = q.x, i = q.y, j = q.z, k = q.w;
    float two_s = 2.0f / (r * r + i * i + j * j + k * k);
    float R00 = 1.0f - two_s * (j * j + k * k);
    float R01 = two_s * (i * j - k * r);
    float R02 = two_s * (i * k + j * r);
    float R10 = two_s * (i * j + k * r);
    float R11 = 1.0f - two_s * (i * i + k * k);
    float R12 = two_s * (j * k - i * r);
    float R20 = two_s * (i * k - j * r);
    float R21 = two_s * (j * k + i * r);
    float R22 = 1.0f - two_s * (i * i + j * j);

    float tx = ptrans[bt * 3 + 0];
    float ty = ptrans[bt * 3 + 1];
    float tz = ptrans[bt * 3 + 2];

    // 4 points = 12 floats = 3 x float4 (48 B, 16B-aligned since pt0*12B = g*48B)
    size_t base = (size_t)pt0 * 3;
    const float4* pp = reinterpret_cast<const float4*>(pred + base);
    const float4* cc = reinterpret_cast<const float4*>(cenp + base);
    float4 p0 = pp[0], p1 = pp[1], p2 = pp[2];
    float4 c0 = cc[0], c1 = cc[1], c2 = cc[2];

    float pf[12] = {p0.x, p0.y, p0.z, p0.w, p1.x, p1.y, p1.z, p1.w, p2.x, p2.y, p2.z, p2.w};
    float cf[12] = {c0.x, c0.y, c0.z, c0.w, c1.x, c1.y, c1.z, c1.w, c2.x, c2.y, c2.z, c2.w};
    float of[12];

#pragma unroll
    for (int m = 0; m < 4; ++m) {
        float x = pf[3 * m + 0] - cf[3 * m + 0];
        float y = pf[3 * m + 1] - cf[3 * m + 1];
        float z = pf[3 * m + 2] - cf[3 * m + 2];
        // row-vector: out_j = sum_i p_i * R[i][j]
        of[3 * m + 0] = x * R00 + y * R10 + z * R20 + tx + cf[3 * m + 0];
        of[3 * m + 1] = x * R01 + y * R11 + z * R21 + ty + cf[3 * m + 1];
        of[3 * m + 2] = x * R02 + y * R12 + z * R22 + tz + cf[3 * m + 2];
    }

    float4* oo = reinterpret_cast<float4*>(out + base);
    oo[0] = make_float4(of[0], of[1], of[2], of[3]);
    oo[1] = make_float4(of[4], of[5], of[6], of[7]);
    oo[2] = make_float4(of[8], of[9], of[10], of[11]);
}

extern "C" void kernel_launch(void* const* d_in, const int* in_sizes, int n_in,
                              void* d_out, int out_size, void* d_ws, size_t ws_size,
                              hipStream_t stream) {
    const float* pred   = (const float*)d_in[0];
    const float* cenp   = (const float*)d_in[1];
    const float* dofs   = (const float*)d_in[2];
    const float* ptrans = (const float*)d_in[3];
    float* out = (float*)d_out;

    int total_points = in_sizes[0] / 3;       // B*T*N = 4,194,304
    int total_groups = total_points / 4;      // 1,048,576 threads
    int block = 256;
    int grid = (total_groups + block - 1) / block;  // 4096 blocks

    tooth_assembler_kernel<<<grid, block, 0, stream>>>(pred, cenp, dofs, ptrans, out, total_groups);
}